// Round 5
// baseline (174.728 us; speedup 1.0000x reference)
//
#include <hip/hip_runtime.h>

using half2v  = __attribute__((ext_vector_type(2))) _Float16;
using half4   = __attribute__((ext_vector_type(4))) _Float16;
using half8   = __attribute__((ext_vector_type(8))) _Float16;
using floatx4 = __attribute__((ext_vector_type(4))) float;

constexpr int BATCH = 2;
constexpr int NPOS  = 96 * 96;    // 9216
constexpr int NT    = NPOS / 16;  // 576 sixteen-wide i-tiles
constexpr int NST   = NPOS / 32;  // 288 thirty-two-wide j-steps

#define EXP2(x) __builtin_amdgcn_exp2f(x)

// Pack exp2 of two E-MFMA outputs (e=0, e=1) into one K=32 B-operand.
// Quad q of lane l holds k = 8q+idx; E_e reg r at quad q is j = 8q+4e+r. So
// idx 0..3 <- exp(e0 regs), idx 4..7 <- exp(e1 regs). No cross-lane moves.
__device__ inline half8 p8_of(floatx4 e0, floatx4 e1) {
    half2v a0 = __builtin_bit_cast(half2v,
        __builtin_amdgcn_cvt_pkrtz(EXP2(e0[0]), EXP2(e0[1])));
    half2v a1 = __builtin_bit_cast(half2v,
        __builtin_amdgcn_cvt_pkrtz(EXP2(e0[2]), EXP2(e0[3])));
    half2v a2 = __builtin_bit_cast(half2v,
        __builtin_amdgcn_cvt_pkrtz(EXP2(e1[0]), EXP2(e1[1])));
    half2v a3 = __builtin_bit_cast(half2v,
        __builtin_amdgcn_cvt_pkrtz(EXP2(e1[2]), EXP2(e1[3])));
    half8 p = {a0[0], a0[1], a1[0], a1[1], a2[0], a2[1], a3[0], a3[1]};
    return p;
}

// ---------------------------------------------------------------------------
// K1: QKV projection. V fp32 pos-major. Kf: B-operand of E (i = l&15,
// d = 4*(l>>4)+r, padded 8->16). Qf: A-operand rows j-PERMUTED:
// frag (js,e) row m holds q of j = 32js + 8*(m>>2) + 4e + (m&3), scaled log2e.
// Per-lane storage: half8 at (b*NST+js)*64 + lane = [e0 half4 | e1 half4].
// ---------------------------------------------------------------------------
__global__ __launch_bounds__(256) void qkv_kernel(
    const float* __restrict__ x,
    const float* __restrict__ wq, const float* __restrict__ bq,
    const float* __restrict__ wk, const float* __restrict__ bk,
    const float* __restrict__ wv, const float* __restrict__ bv,
    _Float16* __restrict__ Qf, _Float16* __restrict__ Kf,
    float* __restrict__ V)
{
    __shared__ float W[80][64];
    __shared__ float bias[80];
    const int tid = threadIdx.x;
    for (int idx = tid; idx < 80 * 64; idx += 256) {
        int o = idx >> 6, c = idx & 63;
        float w;
        if (o < 8)       w = wq[o * 64 + c];
        else if (o < 16) w = wk[(o - 8) * 64 + c];
        else             w = wv[(o - 16) * 64 + c];
        W[o][c] = w;
    }
    if (tid < 80) {
        float bb;
        if (tid < 8)       bb = bq[tid];
        else if (tid < 16) bb = bk[tid - 8];
        else               bb = bv[tid - 16];
        bias[tid] = bb;
    }
    __syncthreads();

    const int part = tid >> 6;                    // wave-uniform
    const int pos  = blockIdx.x * 64 + (tid & 63);
    const int b = pos / NPOS;
    const int i = pos - b * NPOS;

    float xr[64];
    #pragma unroll
    for (int c = 0; c < 64; ++c)
        xr[c] = x[(size_t)(b * 64 + c) * NPOS + i];

    #define DOT(O, S) { S = bias[O]; \
        _Pragma("unroll") \
        for (int c4 = 0; c4 < 16; ++c4) { \
            float4 w4 = *(const float4*)&W[O][c4 * 4]; \
            S += w4.x * xr[c4*4+0] + w4.y * xr[c4*4+1] \
               + w4.z * xr[c4*4+2] + w4.w * xr[c4*4+3]; } }

    if (part == 0) {
        float qk[16];
        #pragma unroll
        for (int o = 0; o < 16; ++o) DOT(o, qk[o]);
        #pragma unroll
        for (int o = 16; o < 20; ++o) { float s; DOT(o, s); V[(size_t)pos * 64 + (o - 16)] = s; }
        constexpr float LOG2E = 1.44269504088896f;
        // Q fragment (permuted rows)
        {
            const int js = i >> 5, off = i & 31;
            const int qh8 = off >> 3, e = (off >> 2) & 1, r = off & 3;
            const int m = 4 * qh8 + r;
            half4* q4 = (half4*)Qf;
            #pragma unroll
            for (int g = 0; g < 4; ++g) {
                half4 qh;
                #pragma unroll
                for (int rr = 0; rr < 4; ++rr)
                    qh[rr] = (g < 2) ? (_Float16)(qk[4*g + rr] * LOG2E) : (_Float16)0.f;
                q4[(((size_t)(b * NST + js) * 64) + m + 16 * g) * 2 + e] = qh;
            }
        }
        // K fragment (natural i order)
        {
            const int it = i >> 4, il = i & 15;
            half4* k4 = (half4*)Kf;
            #pragma unroll
            for (int g = 0; g < 4; ++g) {
                half4 kh;
                #pragma unroll
                for (int rr = 0; rr < 4; ++rr)
                    kh[rr] = (g < 2) ? (_Float16)qk[8 + 4*g + rr] : (_Float16)0.f;
                k4[((size_t)(b * NT + it) * 64) + il + 16 * g] = kh;
            }
        }
    } else {
        #pragma unroll
        for (int oo = 0; oo < 20; ++oo) {
            int o = part * 20 + oo;
            float s; DOT(o, s);
            V[(size_t)pos * 64 + (o - 16)] = s;
        }
    }
    #undef DOT
}

// ---------------------------------------------------------------------------
// K2: denominators. Block = 64 j (2 j-steps x 2 e-frags), i-half per z;
// wave = i-eighth, 4 persistent Q-frags, kf reused 4x. Lp write index maps
// the j-permutation back: (s,g,r) -> loc = (s>>1)*32 + 8g + 4*(s&1) + r.
// ---------------------------------------------------------------------------
__global__ __launch_bounds__(256, 4) void denom_kernel(
    const _Float16* __restrict__ Qf, const _Float16* __restrict__ Kf,
    float* __restrict__ Lp)
{
    __shared__ float LpS[4][64];
    const int tid = threadIdx.x;
    const int w = tid >> 6, l = tid & 63;
    const int jgl = blockIdx.x;         // 0..143
    const int b   = blockIdx.y;
    const int ih  = blockIdx.z;
    const half8* __restrict__ qfb = (const half8*)Qf + (size_t)b * NST * 64;
    const half4* __restrict__ kfb = (const half4*)Kf + (size_t)b * NT * 64;

    half8 qvA = qfb[(size_t)(jgl * 2 + 0) * 64 + l];
    half8 qvB = qfb[(size_t)(jgl * 2 + 1) * 64 + l];
    half4 q0 = __builtin_shufflevector(qvA, qvA, 0, 1, 2, 3);
    half4 q1 = __builtin_shufflevector(qvA, qvA, 4, 5, 6, 7);
    half4 q2 = __builtin_shufflevector(qvB, qvB, 0, 1, 2, 3);
    half4 q3 = __builtin_shufflevector(qvB, qvB, 4, 5, 6, 7);

    float sum[4][4];
    #pragma unroll
    for (int s = 0; s < 4; ++s)
        #pragma unroll
        for (int r = 0; r < 4; ++r) sum[s][r] = 0.f;

    #define DSTEP(KF) do { \
        floatx4 z = {0.f,0.f,0.f,0.f}; \
        floatx4 e0 = __builtin_amdgcn_mfma_f32_16x16x16f16(q0, KF, z, 0,0,0); \
        floatx4 e1 = __builtin_amdgcn_mfma_f32_16x16x16f16(q1, KF, z, 0,0,0); \
        floatx4 e2 = __builtin_amdgcn_mfma_f32_16x16x16f16(q2, KF, z, 0,0,0); \
        floatx4 e3 = __builtin_amdgcn_mfma_f32_16x16x16f16(q3, KF, z, 0,0,0); \
        _Pragma("unroll") \
        for (int r = 0; r < 4; ++r) { \
            sum[0][r] += EXP2(e0[r]); sum[1][r] += EXP2(e1[r]); \
            sum[2][r] += EXP2(e2[r]); sum[3][r] += EXP2(e3[r]); } \
    } while (0)

    const half4* kp = kfb + (size_t)(ih * (NT/2) + w) * 64 + l;
    half4 kf = *kp;
    for (int k = 0; k < 71; ++k) {
        kp += 256;
        half4 kn = *kp;
        DSTEP(kf);
        kf = kn;
    }
    DSTEP(kf);
    #undef DSTEP

    #pragma unroll
    for (int s = 0; s < 4; ++s)
        #pragma unroll
        for (int r = 0; r < 4; ++r)
            #pragma unroll
            for (int m = 1; m < 16; m <<= 1)
                sum[s][r] += __shfl_xor(sum[s][r], m, 64);

    if ((l & 15) == 0) {
        const int g = l >> 4;
        #pragma unroll
        for (int s = 0; s < 4; ++s)
            #pragma unroll
            for (int r = 0; r < 4; ++r)
                LpS[w][(s >> 1) * 32 + 8 * g + 4 * (s & 1) + r] = sum[s][r];
    }
    __syncthreads();
    if (tid < 64) {
        float tot = LpS[0][tid] + LpS[1][tid] + LpS[2][tid] + LpS[3][tid];
        Lp[((size_t)ih * BATCH + b) * NPOS + jgl * 64 + tid] = tot;
    }
}

// ---------------------------------------------------------------------------
// K3: V' fragments in K=32 A-operand order:
//   Vf[b][js][ct][lane][idx] = V[j = 32js+8*(l>>4)+idx][c = 16ct+(l&15)] / L[j]
// ---------------------------------------------------------------------------
__global__ __launch_bounds__(256) void prepv_kernel(
    const float* __restrict__ V, const float* __restrict__ Lp,
    _Float16* __restrict__ Vf)
{
    const int tid = blockIdx.x * 256 + threadIdx.x;
    const int b   = tid / (NST * 256);
    const int rem = tid - b * (NST * 256);
    const int js  = rem >> 8;
    const int ct  = (rem >> 6) & 3;
    const int l   = rem & 63;
    const int g = l >> 4, c = 16 * ct + (l & 15);
    half8 o;
    #pragma unroll
    for (int idx = 0; idx < 8; ++idx) {
        int j = 32 * js + 8 * g + idx;
        float Lv = Lp[(size_t)b * NPOS + j] + Lp[(size_t)(BATCH + b) * NPOS + j];
        o[idx] = (_Float16)(V[((size_t)b * NPOS + j) * 64 + c] / Lv);
    }
    *(half8*)&Vf[(size_t)tid * 8] = o;
}

// ---------------------------------------------------------------------------
// K4: attention. Block = 64 i x j-half; wave = j-quarter-of-half holding all
// 4 i-subtiles. Per 32-j step: 8 E (16x16x16, permuted-Q) -> 32 exp ->
// 4 half8 P (in-register) -> 16 PV (16x16x32). Depth-1 prefetch.
// Epilogue: 3-round rotate-combine in 17.4 KB LDS, write ACC[half].
// ---------------------------------------------------------------------------
__global__ __launch_bounds__(256, 3) void attn_kernel(
    const _Float16* __restrict__ Qf, const _Float16* __restrict__ Kf,
    const _Float16* __restrict__ Vf, float* __restrict__ ACC)
{
    __shared__ float red[4][64][17];
    const int tid = threadIdx.x;
    const int w = tid >> 6, l = tid & 63;
    const int igl = blockIdx.x;        // 0..143
    const int b   = blockIdx.y;
    const int h   = blockIdx.z;
    const int it0 = igl * 4, i0 = igl * 64;
    const half8* __restrict__ qfb = (const half8*)Qf + (size_t)b * NST * 64;
    const half4* __restrict__ kfb = (const half4*)Kf + (size_t)b * NT * 64;
    const half8* __restrict__ vfb = (const half8*)Vf + (size_t)b * NST * 256;

    half4 kf[4];
    #pragma unroll
    for (int s = 0; s < 4; ++s) kf[s] = kfb[(size_t)(it0 + s) * 64 + l];

    floatx4 acc[4][4];
    #pragma unroll
    for (int s = 0; s < 4; ++s)
        #pragma unroll
        for (int t = 0; t < 4; ++t)
            acc[s][t] = (floatx4){0.f, 0.f, 0.f, 0.f};

    #define ASTEP(QV, V0, V1, V2, V3) do { \
        half4 qe0 = __builtin_shufflevector(QV, QV, 0, 1, 2, 3); \
        half4 qe1 = __builtin_shufflevector(QV, QV, 4, 5, 6, 7); \
        floatx4 z = {0.f,0.f,0.f,0.f}; \
        _Pragma("unroll") \
        for (int it = 0; it < 4; ++it) { \
            floatx4 e0 = __builtin_amdgcn_mfma_f32_16x16x16f16(qe0, kf[it], z, 0,0,0); \
            floatx4 e1 = __builtin_amdgcn_mfma_f32_16x16x16f16(qe1, kf[it], z, 0,0,0); \
            half8 p = p8_of(e0, e1); \
            acc[it][0] = __builtin_amdgcn_mfma_f32_16x16x32_f16(V0, p, acc[it][0], 0,0,0); \
            acc[it][1] = __builtin_amdgcn_mfma_f32_16x16x32_f16(V1, p, acc[it][1], 0,0,0); \
            acc[it][2] = __builtin_amdgcn_mfma_f32_16x16x32_f16(V2, p, acc[it][2], 0,0,0); \
            acc[it][3] = __builtin_amdgcn_mfma_f32_16x16x32_f16(V3, p, acc[it][3], 0,0,0); \
        } \
    } while (0)

    const half8* qp = qfb + (size_t)(h * 144 + w) * 64 + l;
    const half8* vp = vfb + (size_t)(h * 144 + w) * 256 + l;
    half8 qv = *qp;
    half8 v0 = vp[0], v1 = vp[64], v2 = vp[128], v3 = vp[192];
    for (int k = 0; k < 35; ++k) {
        qp += 256; vp += 1024;
        half8 qn  = *qp;
        half8 v0n = vp[0], v1n = vp[64], v2n = vp[128], v3n = vp[192];
        ASTEP(qv, v0, v1, v2, v3);
        qv = qn; v0 = v0n; v1 = v1n; v2 = v2n; v3 = v3n;
    }
    ASTEP(qv, v0, v1, v2, v3);
    #undef ASTEP

    // 3-round rotate-combine: wave w ends with the full sum for subtile w.
    #pragma unroll
    for (int k = 1; k < 4; ++k) {
        const int src = (w + k) & 3;     // shard this wave contributes
        #pragma unroll
        for (int t = 0; t < 4; ++t)
            #pragma unroll
            for (int r = 0; r < 4; ++r)
                red[w][l][t * 4 + r] = acc[src][t][r];
        __syncthreads();
        const int from = (w - k) & 3;    // wave that wrote OUR subtile
        #pragma unroll
        for (int t = 0; t < 4; ++t)
            #pragma unroll
            for (int r = 0; r < 4; ++r)
                acc[w][t][r] += red[from][l][t * 4 + r];
        __syncthreads();
    }

    const int iq = i0 + 16 * w + (l & 15);
    #pragma unroll
    for (int t = 0; t < 4; ++t)
        #pragma unroll
        for (int r = 0; r < 4; ++r) {
            int c = 16 * t + 4 * (l >> 4) + r;
            ACC[(((size_t)h * BATCH + b) * 64 + c) * NPOS + iq] = acc[w][t][r];
        }
}

// ---------------------------------------------------------------------------
// K5: out = gamma * (ACC[0] + ACC[1]) + x   (streaming float4)
// ---------------------------------------------------------------------------
__global__ __launch_bounds__(256) void finalize_kernel(
    const float* __restrict__ ACC, const float* __restrict__ x,
    const float* __restrict__ gamma, float* __restrict__ out)
{
    const size_t idx = (size_t)blockIdx.x * 256 + threadIdx.x;
    constexpr size_t HALF4 = (size_t)BATCH * 64 * NPOS / 4;   // 294912
    const float g = gamma[0];
    float4 a0 = ((const float4*)ACC)[idx];
    float4 a1 = ((const float4*)ACC)[HALF4 + idx];
    float4 xv = ((const float4*)x)[idx];
    float4 o;
    o.x = g * (a0.x + a1.x) + xv.x;
    o.y = g * (a0.y + a1.y) + xv.y;
    o.z = g * (a0.z + a1.z) + xv.z;
    o.w = g * (a0.w + a1.w) + xv.w;
    ((float4*)out)[idx] = o;
}

// ---------------------------------------------------------------------------
extern "C" void kernel_launch(void* const* d_in, const int* in_sizes, int n_in,
                              void* d_out, int out_size, void* d_ws, size_t ws_size,
                              hipStream_t stream)
{
    const float* x     = (const float*)d_in[0];
    const float* wq    = (const float*)d_in[1];
    const float* bq    = (const float*)d_in[2];
    const float* wk    = (const float*)d_in[3];
    const float* bk    = (const float*)d_in[4];
    const float* wv    = (const float*)d_in[5];
    const float* bv    = (const float*)d_in[6];
    const float* gamma = (const float*)d_in[7];
    float* out = (float*)d_out;

    char* wsb = (char*)d_ws;
    float*    V   = (float*)wsb;                         // 4,718,592 B
    float*    Lp  = (float*)(wsb + 4718592);             //   147,456 B
    _Float16* Qf  = (_Float16*)(wsb + 4866048);          //   589,824 B
    _Float16* Kf  = (_Float16*)(wsb + 5455872);          //   589,824 B
    _Float16* Vf  = (_Float16*)(wsb + 6045696);          // 2,359,296 B
    float*    ACC = (float*)(wsb + 8404992);             // 9,437,184 B

    qkv_kernel<<<dim3(BATCH * NPOS / 64), 256, 0, stream>>>(
        x, wq, bq, wk, bk, wv, bv, Qf, Kf, V);

    denom_kernel<<<dim3(NST / 2, BATCH, 2), 256, 0, stream>>>(Qf, Kf, Lp);

    prepv_kernel<<<dim3(BATCH * NST, 1, 1), 256, 0, stream>>>(V, Lp, Vf);

    attn_kernel<<<dim3(NT / 4, BATCH, 2), 256, 0, stream>>>(Qf, Kf, Vf, ACC);

    finalize_kernel<<<dim3(BATCH * 64 * NPOS / 1024), 256, 0, stream>>>(
        ACC, x, gamma, out);
}

// Round 6
// 150.230 us; speedup vs baseline: 1.1631x; 1.1631x over previous
//
#include <hip/hip_runtime.h>

using half2v  = __attribute__((ext_vector_type(2))) _Float16;
using half4   = __attribute__((ext_vector_type(4))) _Float16;
using half8   = __attribute__((ext_vector_type(8))) _Float16;
using floatx4 = __attribute__((ext_vector_type(4))) float;

constexpr int BATCH = 2;
constexpr int NPOS  = 96 * 96;    // 9216
constexpr int NT    = NPOS / 16;  // 576 sixteen-wide i-tiles
constexpr int NST   = NPOS / 32;  // 288 thirty-two-wide j-steps

#define EXP2(x) __builtin_amdgcn_exp2f(x)

// Pack exp2 of two E-MFMA outputs (e=0, e=1) into one K=32 B-operand.
__device__ inline half8 p8_of(floatx4 e0, floatx4 e1) {
    half2v a0 = __builtin_bit_cast(half2v,
        __builtin_amdgcn_cvt_pkrtz(EXP2(e0[0]), EXP2(e0[1])));
    half2v a1 = __builtin_bit_cast(half2v,
        __builtin_amdgcn_cvt_pkrtz(EXP2(e0[2]), EXP2(e0[3])));
    half2v a2 = __builtin_bit_cast(half2v,
        __builtin_amdgcn_cvt_pkrtz(EXP2(e1[0]), EXP2(e1[1])));
    half2v a3 = __builtin_bit_cast(half2v,
        __builtin_amdgcn_cvt_pkrtz(EXP2(e1[2]), EXP2(e1[3])));
    half8 p = {a0[0], a0[1], a1[0], a1[1], a2[0], a2[1], a3[0], a3[1]};
    return p;
}

// ---------------------------------------------------------------------------
// K1: QKV projection. 576 blocks x 32 positions; 8 thread-parts x 10 outputs.
// LDS-transpose then write: Qf (j-permuted A-layout, log2e-scaled, d>=8 -> 0),
// Kf (B-layout, d=8,9 -> 1.0 for the Q-augment trick), Vf (raw f16, K=32
// A-layout). No fp32 V buffer.
// ---------------------------------------------------------------------------
__global__ __launch_bounds__(256) void qkv_kernel(
    const float* __restrict__ x,
    const float* __restrict__ wq, const float* __restrict__ bq,
    const float* __restrict__ wk, const float* __restrict__ bk,
    const float* __restrict__ wv, const float* __restrict__ bv,
    _Float16* __restrict__ Qf, _Float16* __restrict__ Kf,
    _Float16* __restrict__ Vf)
{
    __shared__ float W[80][64];
    __shared__ float bias[80];
    __shared__ float qs[32][8];
    __shared__ float ks[32][8];
    __shared__ _Float16 vs[32][64];
    const int tid = threadIdx.x;
    for (int idx = tid; idx < 80 * 64; idx += 256) {
        int o = idx >> 6, c = idx & 63;
        float w;
        if (o < 8)       w = wq[o * 64 + c];
        else if (o < 16) w = wk[(o - 8) * 64 + c];
        else             w = wv[(o - 16) * 64 + c];
        W[o][c] = w;
    }
    if (tid < 80) {
        float bb;
        if (tid < 8)       bb = bq[tid];
        else if (tid < 16) bb = bk[tid - 8];
        else               bb = bv[tid - 16];
        bias[tid] = bb;
    }
    __syncthreads();

    const int js = blockIdx.x;          // 0..287
    const int b  = blockIdx.y;
    const int part = tid >> 5;          // 0..7
    const int jl   = tid & 31;
    const int i    = js * 32 + jl;

    float xr[64];
    #pragma unroll
    for (int c = 0; c < 64; ++c)
        xr[c] = x[(size_t)(b * 64 + c) * NPOS + i];

    #pragma unroll
    for (int q = 0; q < 10; ++q) {
        const int o = part * 10 + q;
        float s = bias[o];
        #pragma unroll
        for (int c4 = 0; c4 < 16; ++c4) {
            float4 w4 = *(const float4*)&W[o][c4 * 4];
            s += w4.x * xr[c4*4+0] + w4.y * xr[c4*4+1]
               + w4.z * xr[c4*4+2] + w4.w * xr[c4*4+3];
        }
        if (o < 8)       qs[jl][o] = s;
        else if (o < 16) ks[jl][o - 8] = s;
        else             vs[jl][o - 16] = (_Float16)s;
    }
    __syncthreads();

    const size_t tile = (size_t)b * NST + js;
    // Vf: one half8 per thread.  Vf[tile][ct][l][idx] = v[8g+idx][16ct+cl]
    {
        const int ct = tid >> 6, l = tid & 63;
        const int g = l >> 4, cl = l & 15;
        half8 o8;
        #pragma unroll
        for (int idx = 0; idx < 8; ++idx)
            o8[idx] = vs[8 * g + idx][16 * ct + cl];
        *(half8*)&Vf[(tile * 256 + ct * 64 + l) * 8] = o8;
    }
    // Qf: threads 0..127 (lane l, frag e). j = 8*(m>>2)+4e+(m&3), m=l&15.
    if (tid < 128) {
        const int l = tid >> 1, e = tid & 1;
        const int m = l & 15, g = l >> 4;
        const int jsrc = 8 * (m >> 2) + 4 * e + (m & 3);
        constexpr float LOG2E = 1.44269504088896f;
        half4 qh;
        #pragma unroll
        for (int r = 0; r < 4; ++r)
            qh[r] = (g < 2) ? (_Float16)(qs[jsrc][4 * g + r] * LOG2E)
                            : (_Float16)0.f;
        ((half4*)Qf)[(tile * 64 + l) * 2 + e] = qh;
    } else {
        // Kf: threads 128..255 -> 2 sixteen-wide i-tiles
        const int t = tid - 128;
        const int ht = t >> 6, l = t & 63;
        const int il = l & 15, g = l >> 4;
        const int it = js * 2 + ht;
        half4 kh;
        #pragma unroll
        for (int r = 0; r < 4; ++r) {
            if (g < 2)       kh[r] = (_Float16)ks[16 * ht + il][4 * g + r];
            else if (g == 2) kh[r] = (r < 2) ? (_Float16)1.f : (_Float16)0.f;
            else             kh[r] = (_Float16)0.f;
        }
        ((half4*)Kf)[(size_t)(b * NT + it) * 64 + l] = kh;
    }
}

// ---------------------------------------------------------------------------
// K2: denominators (partials). Same as R5: block = 64 j x i-half, 4 waves,
// Qf[d>=8]=0 at this point so the augment channels contribute nothing.
// ---------------------------------------------------------------------------
__global__ __launch_bounds__(256, 4) void denom_kernel(
    const _Float16* __restrict__ Qf, const _Float16* __restrict__ Kf,
    float* __restrict__ Lp)
{
    __shared__ float LpS[4][64];
    const int tid = threadIdx.x;
    const int w = tid >> 6, l = tid & 63;
    const int jgl = blockIdx.x;         // 0..143
    const int b   = blockIdx.y;
    const int ih  = blockIdx.z;
    const half8* __restrict__ qfb = (const half8*)Qf + (size_t)b * NST * 64;
    const half4* __restrict__ kfb = (const half4*)Kf + (size_t)b * NT * 64;

    half8 qvA = qfb[(size_t)(jgl * 2 + 0) * 64 + l];
    half8 qvB = qfb[(size_t)(jgl * 2 + 1) * 64 + l];
    half4 q0 = __builtin_shufflevector(qvA, qvA, 0, 1, 2, 3);
    half4 q1 = __builtin_shufflevector(qvA, qvA, 4, 5, 6, 7);
    half4 q2 = __builtin_shufflevector(qvB, qvB, 0, 1, 2, 3);
    half4 q3 = __builtin_shufflevector(qvB, qvB, 4, 5, 6, 7);

    float sum[4][4];
    #pragma unroll
    for (int s = 0; s < 4; ++s)
        #pragma unroll
        for (int r = 0; r < 4; ++r) sum[s][r] = 0.f;

    #define DSTEP(KF) do { \
        floatx4 z = {0.f,0.f,0.f,0.f}; \
        floatx4 e0 = __builtin_amdgcn_mfma_f32_16x16x16f16(q0, KF, z, 0,0,0); \
        floatx4 e1 = __builtin_amdgcn_mfma_f32_16x16x16f16(q1, KF, z, 0,0,0); \
        floatx4 e2 = __builtin_amdgcn_mfma_f32_16x16x16f16(q2, KF, z, 0,0,0); \
        floatx4 e3 = __builtin_amdgcn_mfma_f32_16x16x16f16(q3, KF, z, 0,0,0); \
        _Pragma("unroll") \
        for (int r = 0; r < 4; ++r) { \
            sum[0][r] += EXP2(e0[r]); sum[1][r] += EXP2(e1[r]); \
            sum[2][r] += EXP2(e2[r]); sum[3][r] += EXP2(e3[r]); } \
    } while (0)

    const half4* kp = kfb + (size_t)(ih * (NT/2) + w) * 64 + l;
    half4 kf = *kp;
    for (int k = 0; k < 71; ++k) {
        kp += 256;
        half4 kn = *kp;
        DSTEP(kf);
        kf = kn;
    }
    DSTEP(kf);
    #undef DSTEP

    #pragma unroll
    for (int s = 0; s < 4; ++s)
        #pragma unroll
        for (int r = 0; r < 4; ++r)
            #pragma unroll
            for (int m = 1; m < 16; m <<= 1)
                sum[s][r] += __shfl_xor(sum[s][r], m, 64);

    if ((l & 15) == 0) {
        const int g = l >> 4;
        #pragma unroll
        for (int s = 0; s < 4; ++s)
            #pragma unroll
            for (int r = 0; r < 4; ++r)
                LpS[w][(s >> 1) * 32 + 8 * g + 4 * (s & 1) + r] = sum[s][r];
    }
    __syncthreads();
    if (tid < 64) {
        float tot = LpS[0][tid] + LpS[1][tid] + LpS[2][tid] + LpS[3][tid];
        Lp[((size_t)ih * BATCH + b) * NPOS + jgl * 64 + tid] = tot;
    }
}

// ---------------------------------------------------------------------------
// K3: patch. Qf[j][d=8,9] = hi/lo split of -log2(L_j); Kf[d=8,9]=1.0 makes
// every later E-MFMA compute log2e*(q.k) - log2 L, so exp2(E) = p/L.
// ---------------------------------------------------------------------------
__global__ __launch_bounds__(256) void patch_kernel(
    const float* __restrict__ Lp, _Float16* __restrict__ Qf)
{
    const int idx = blockIdx.x * 256 + threadIdx.x;   // 0 .. 18431
    const int b = idx / NPOS;
    const int j = idx - b * NPOS;
    const float L = Lp[(size_t)b * NPOS + j] + Lp[(size_t)(BATCH + b) * NPOS + j];
    const float v = -__log2f(L);
    _Float16 hi = (_Float16)v;
    _Float16 lo = (_Float16)(v - (float)hi);
    const int js = j >> 5, off = j & 31;
    const int m = ((off >> 3) << 2) | (off & 3);
    const int e = (off >> 2) & 1;
    const size_t tile = (size_t)b * NST + js;
    // elements 0,1 of the g=2 half4 -> one aligned half2 store
    half2v hl = {hi, lo};
    ((half2v*)Qf)[((tile * 64 + m + 32) * 2 + e) * 2] = hl;
}

// ---------------------------------------------------------------------------
// K4: attention, direct-out. Grid 768 (exactly 3 blocks/CU), block = 48 i
// (3 subtiles) x 32 c (c-half) x FULL j. XCD swizzle pins batch streams to
// 4 XCDs each. Per wave-step: 6 E + 3 packs + 6 PV(16x16x32), 48B loads.
// Epilogue: 4-wave LDS combine, out = gamma*acc + x. No ACC, no finalize.
// ---------------------------------------------------------------------------
__global__ __launch_bounds__(256, 3) void attn_kernel(
    const _Float16* __restrict__ Qf, const _Float16* __restrict__ Kf,
    const _Float16* __restrict__ Vf,
    const float* __restrict__ x, const float* __restrict__ gamma,
    float* __restrict__ out)
{
    __shared__ float red[4][3][64][9];
    const int s = blockIdx.x;
    const int xcd = s & 7;
    const int b   = xcd >> 2;
    const int r2  = (s >> 3) * 4 + (xcd & 3);   // 0..383
    const int igl = r2 % 192;
    const int ch  = r2 / 192;
    const int tid = threadIdx.x;
    const int w = tid >> 6, l = tid & 63;
    const int it0 = igl * 3, i0 = igl * 48;

    const half8* __restrict__ qfb = (const half8*)Qf + (size_t)b * NST * 64;
    const half4* __restrict__ kfb = (const half4*)Kf + (size_t)b * NT * 64;
    const half8* __restrict__ vfb = (const half8*)Vf + (size_t)b * NST * 256;

    half4 kf[3];
    #pragma unroll
    for (int st = 0; st < 3; ++st) kf[st] = kfb[(size_t)(it0 + st) * 64 + l];

    floatx4 acc[3][2];
    #pragma unroll
    for (int st = 0; st < 3; ++st) {
        acc[st][0] = (floatx4){0.f, 0.f, 0.f, 0.f};
        acc[st][1] = (floatx4){0.f, 0.f, 0.f, 0.f};
    }

    #define ASTEP(QV, V0, V1) do { \
        half4 qe0 = __builtin_shufflevector(QV, QV, 0, 1, 2, 3); \
        half4 qe1 = __builtin_shufflevector(QV, QV, 4, 5, 6, 7); \
        floatx4 z = {0.f,0.f,0.f,0.f}; \
        _Pragma("unroll") \
        for (int st = 0; st < 3; ++st) { \
            floatx4 e0 = __builtin_amdgcn_mfma_f32_16x16x16f16(qe0, kf[st], z, 0,0,0); \
            floatx4 e1 = __builtin_amdgcn_mfma_f32_16x16x16f16(qe1, kf[st], z, 0,0,0); \
            half8 p = p8_of(e0, e1); \
            acc[st][0] = __builtin_amdgcn_mfma_f32_16x16x32_f16(V0, p, acc[st][0], 0,0,0); \
            acc[st][1] = __builtin_amdgcn_mfma_f32_16x16x32_f16(V1, p, acc[st][1], 0,0,0); \
        } \
    } while (0)

    const half8* qp = qfb + (size_t)w * 64 + l;
    const half8* vp = vfb + (size_t)w * 256 + ch * 128 + l;
    half8 qv = *qp;
    half8 v0 = vp[0], v1 = vp[64];
    for (int k = 0; k < 71; ++k) {
        qp += 256; vp += 1024;
        half8 qn  = *qp;
        half8 v0n = vp[0], v1n = vp[64];
        ASTEP(qv, v0, v1);
        qv = qn; v0 = v0n; v1 = v1n;
    }
    ASTEP(qv, v0, v1);
    #undef ASTEP

    // dump all shards, combine, fused epilogue
    #pragma unroll
    for (int st = 0; st < 3; ++st)
        #pragma unroll
        for (int t2 = 0; t2 < 2; ++t2)
            #pragma unroll
            for (int r = 0; r < 4; ++r)
                red[w][st][l][t2 * 4 + r] = acc[st][t2][r];
    __syncthreads();

    if (w < 3) {
        const float g = gamma[0];
        const int iq = i0 + 16 * w + (l & 15);
        #pragma unroll
        for (int t2 = 0; t2 < 2; ++t2)
            #pragma unroll
            for (int r = 0; r < 4; ++r) {
                float v = red[0][w][l][t2*4+r] + red[1][w][l][t2*4+r]
                        + red[2][w][l][t2*4+r] + red[3][w][l][t2*4+r];
                int c = 16 * (2 * ch + t2) + 4 * (l >> 4) + r;
                size_t o = ((size_t)(b * 64 + c)) * NPOS + iq;
                out[o] = g * v + x[o];
            }
    }
}

// ---------------------------------------------------------------------------
extern "C" void kernel_launch(void* const* d_in, const int* in_sizes, int n_in,
                              void* d_out, int out_size, void* d_ws, size_t ws_size,
                              hipStream_t stream)
{
    const float* x     = (const float*)d_in[0];
    const float* wq    = (const float*)d_in[1];
    const float* bq    = (const float*)d_in[2];
    const float* wk    = (const float*)d_in[3];
    const float* bk    = (const float*)d_in[4];
    const float* wv    = (const float*)d_in[5];
    const float* bv    = (const float*)d_in[6];
    const float* gamma = (const float*)d_in[7];
    float* out = (float*)d_out;

    char* wsb = (char*)d_ws;
    _Float16* Qf = (_Float16*)wsb;                       //   589,824 B
    _Float16* Kf = (_Float16*)(wsb + 589824);            //   589,824 B
    _Float16* Vf = (_Float16*)(wsb + 1179648);           // 2,359,296 B
    float*    Lp = (float*)(wsb + 3538944);              //   147,456 B

    qkv_kernel<<<dim3(NST, BATCH), 256, 0, stream>>>(
        x, wq, bq, wk, bk, wv, bv, Qf, Kf, Vf);

    denom_kernel<<<dim3(NST / 2, BATCH, 2), 256, 0, stream>>>(Qf, Kf, Lp);

    patch_kernel<<<dim3(BATCH * NPOS / 256), 256, 0, stream>>>(Lp, Qf);

    attn_kernel<<<dim3(768), 256, 0, stream>>>(Qf, Kf, Vf, x, gamma, out);
}